// Round 2
// baseline (7980.064 us; speedup 1.0000x reference)
//
#include <hip/hip_runtime.h>
#include <hip/hip_bf16.h>

// AdaptFormer — Round 1: correctness hedge.
// Fixes two NaN hypotheses at once:
//  (a) runtime input-dtype detection (bf16 vs f32) with guarded dual-path
//      launches — a detector kernel writes a flag into ws[0]; every
//      input-reading kernel is templated on the weight dtype and returns
//      early unless flag matches.
//  (b) workspace cut 215 MB -> 53 MB: all intermediates bf16 (f32 compute),
//      x-stream chunked 4 x 2048 rows.

#define H_HEADS 12
#define DMODEL 768
#define DFF 3072
#define ADIM 64
#define NLAT 32
#define BATCH 16
#define NA 512
#define NV 196

typedef __hip_bfloat16 bf16;

static __device__ __forceinline__ float bf2f(bf16 v) { return __bfloat162float(v); }
static __device__ __forceinline__ float bflo(unsigned u) { return __uint_as_float(u << 16); }
static __device__ __forceinline__ float bfhi(unsigned u) { return __uint_as_float(u & 0xffff0000u); }

static __device__ __forceinline__ float ld1(const float* p) { return *p; }
static __device__ __forceinline__ float ld1(const bf16* p) { return bf2f(*p); }
static __device__ __forceinline__ void st1(float* p, float v) { *p = v; }
static __device__ __forceinline__ void st1(bf16* p, float v) { *p = __float2bfloat16(v); }
static __device__ __forceinline__ float4 ld4(const float* p) { return *(const float4*)p; }
static __device__ __forceinline__ float4 ld4(const bf16* p) {
    ushort4 u = *(const ushort4*)p;
    return make_float4(bflo(u.x), bflo(u.y), bflo(u.z), bflo(u.w));
}

// ---------------------------------------------------------------------------
// Dtype detector: bf16 N(0,1) halves never have |v| >= 2^17; f32 data read as
// bf16 halves has ~45% huge-exponent values (mantissa-low halves). flag:
// 0 = inputs are bf16, 1 = inputs are f32.
// ---------------------------------------------------------------------------
__global__ void detect_dtype_kernel(const unsigned short* __restrict__ x, int* __restrict__ flag)
{
    if (threadIdx.x == 0 && blockIdx.x == 0) {
        int big = 0;
        for (int i = 0; i < 2048; i++) {
            unsigned e = (x[i] >> 7) & 0xFF;
            if (e >= 0x90) big++;
        }
        flag[0] = (big > 16) ? 1 : 0;
    }
}

// ---------------------------------------------------------------------------
// Fusion stage 1: fused[b,l,:] = softmax(lat[l].concat[b,n] * 768^-0.5) @ concat
// ---------------------------------------------------------------------------
template<typename TIn>
__global__ __launch_bounds__(256)
void fusion_latents_kernel(const int* __restrict__ flag, int want,
                           const TIn* __restrict__ x, const TIn* __restrict__ y,
                           const TIn* __restrict__ lat, float* __restrict__ fused)
{
    if (flag[0] != want) return;
    const int b = blockIdx.x >> 5;
    const int l = blockIdx.x & 31;
    const int tid = threadIdx.x;
    const int NTOT = NA + NV;  // 708

    __shared__ float q[DMODEL];
    __shared__ float sc[NA + NV];
    __shared__ float red[4];

    for (int d = tid; d < DMODEL; d += 256) q[d] = ld1(lat + l * DMODEL + d);
    __syncthreads();

    for (int n = tid; n < NTOT; n += 256) {
        const TIn* rowp = (n < NA)
            ? x + ((size_t)(b * NA + n)) * DMODEL
            : y + ((size_t)(b * NV + (n - NA))) * DMODEL;
        float s = 0.f;
        for (int d = 0; d < DMODEL; d++) s += q[d] * ld1(rowp + d);
        sc[n] = s * 0.03608439182435161f;  // 768^-0.5
    }
    __syncthreads();

    float mx = -1e30f;
    for (int n = tid; n < NTOT; n += 256) mx = fmaxf(mx, sc[n]);
    #pragma unroll
    for (int off = 32; off; off >>= 1) mx = fmaxf(mx, __shfl_xor(mx, off));
    if ((tid & 63) == 0) red[tid >> 6] = mx;
    __syncthreads();
    mx = fmaxf(fmaxf(red[0], red[1]), fmaxf(red[2], red[3]));
    __syncthreads();
    float ds = 0.f;
    for (int n = tid; n < NTOT; n += 256) { float e = __expf(sc[n] - mx); sc[n] = e; ds += e; }
    #pragma unroll
    for (int off = 32; off; off >>= 1) ds += __shfl_xor(ds, off);
    __syncthreads();
    if ((tid & 63) == 0) red[tid >> 6] = ds;
    __syncthreads();
    const float inv = 1.0f / (red[0] + red[1] + red[2] + red[3]);

    float a0 = 0.f, a1 = 0.f, a2 = 0.f;
    for (int n = 0; n < NTOT; n++) {
        const TIn* rowp = (n < NA)
            ? x + ((size_t)(b * NA + n)) * DMODEL
            : y + ((size_t)(b * NV + (n - NA))) * DMODEL;
        const float pn = sc[n];
        a0 += pn * ld1(rowp + tid);
        a1 += pn * ld1(rowp + tid + 256);
        a2 += pn * ld1(rowp + tid + 512);
    }
    float* o = fused + (size_t)blockIdx.x * DMODEL;
    o[tid] = a0 * inv; o[tid + 256] = a1 * inv; o[tid + 512] = a2 * inv;
}

// ---------------------------------------------------------------------------
// Fusion stage 2: out[b,n,:] = t + scale * softmax(t.fused * 768^-0.5) @ fused
// out is bf16 workspace.
// ---------------------------------------------------------------------------
template<typename TIn>
__global__ __launch_bounds__(256)
void attend_fused_kernel(const int* __restrict__ flag, int want,
                         const TIn* __restrict__ t, const float* __restrict__ fused,
                         const TIn* __restrict__ scale_p, bf16* __restrict__ out, int Npb)
{
    if (flag[0] != want) return;
    const int tid = threadIdx.x;
    const int gid = blockIdx.x;
    const int b = gid / Npb;
    const TIn* row = t + (size_t)gid * DMODEL;
    const float* fb = fused + (size_t)b * NLAT * DMODEL;

    __shared__ float q[DMODEL];
    __shared__ float p[NLAT];

    for (int d = tid; d < DMODEL; d += 256) q[d] = ld1(row + d);
    __syncthreads();

    const int g = tid >> 3, li = tid & 7;
    float s = 0.f;
    const float* fr = fb + (size_t)g * DMODEL;
    for (int d = li; d < DMODEL; d += 8) s += q[d] * fr[d];
    s += __shfl_xor(s, 1); s += __shfl_xor(s, 2); s += __shfl_xor(s, 4);
    if (li == 0) p[g] = s * 0.03608439182435161f;
    __syncthreads();

    float mx = -1e30f;
    #pragma unroll
    for (int l = 0; l < NLAT; l++) mx = fmaxf(mx, p[l]);
    float w[NLAT];
    float den = 0.f;
    #pragma unroll
    for (int l = 0; l < NLAT; l++) { w[l] = __expf(p[l] - mx); den += w[l]; }
    const float sA = ld1(scale_p) / den;

    float a0 = 0.f, a1 = 0.f, a2 = 0.f;
    #pragma unroll
    for (int l = 0; l < NLAT; l++) {
        const float* fv = fb + (size_t)l * DMODEL;
        a0 += w[l] * fv[tid];
        a1 += w[l] * fv[tid + 256];
        a2 += w[l] * fv[tid + 512];
    }
    bf16* o = out + (size_t)gid * DMODEL;
    st1(o + tid,       q[tid]       + sA * a0);
    st1(o + tid + 256, q[tid + 256] + sA * a1);
    st1(o + tid + 512, q[tid + 512] + sA * a2);
}

// ---------------------------------------------------------------------------
// LayerNorm: in bf16 ws [rows,768] -> out bf16 ws; gamma/beta raw inputs (TW)
// ---------------------------------------------------------------------------
template<typename TW>
__global__ __launch_bounds__(256)
void ln_kernel(const int* __restrict__ flag, int want,
               const bf16* __restrict__ in, const TW* __restrict__ g,
               const TW* __restrict__ bta, bf16* __restrict__ out)
{
    if (flag[0] != want) return;
    const int tid = threadIdx.x;
    const bf16* p = in + (size_t)blockIdx.x * DMODEL;
    const float v0 = bf2f(p[tid]), v1 = bf2f(p[tid + 256]), v2 = bf2f(p[tid + 512]);
    float s = v0 + v1 + v2;
    float sq = v0 * v0 + v1 * v1 + v2 * v2;
    #pragma unroll
    for (int off = 32; off; off >>= 1) { s += __shfl_xor(s, off); sq += __shfl_xor(sq, off); }
    __shared__ float rs[4], rq[4];
    if ((tid & 63) == 0) { rs[tid >> 6] = s; rq[tid >> 6] = sq; }
    __syncthreads();
    s = rs[0] + rs[1] + rs[2] + rs[3];
    sq = rq[0] + rq[1] + rq[2] + rq[3];
    const float mean = s * (1.0f / DMODEL);
    const float var = sq * (1.0f / DMODEL) - mean * mean;
    const float r = rsqrtf(var + 1e-6f);
    bf16* o = out + (size_t)blockIdx.x * DMODEL;
    st1(o + tid,       (v0 - mean) * r * ld1(g + tid)       + ld1(bta + tid));
    st1(o + tid + 256, (v1 - mean) * r * ld1(g + tid + 256) + ld1(bta + tid + 256));
    st1(o + tid + 512, (v2 - mean) * r * ld1(g + tid + 512) + ld1(bta + tid + 512));
}

// ---------------------------------------------------------------------------
// MHSA core on bf16 qkv ws [Mc,2304] ([q|k|v] x head*64+d), out bf16 [Mc,768].
// Chunk-local: rows are whole batch items. Unguarded (ws-only, NaN-safe on
// poisoned data: 0xAA bf16 = -3e-13 -> uniform softmax, no Inf).
// ---------------------------------------------------------------------------
__global__ __launch_bounds__(64)
void mhsa_attn_kernel(const bf16* __restrict__ qkv, bf16* __restrict__ o, int Npb)
{
    const int lane = threadIdx.x;
    const int gid = blockIdx.x;
    const int h = gid % H_HEADS;
    const int rowtok = gid / H_HEADS;
    const int b = rowtok / Npb;   // batch item within chunk

    __shared__ float q[64];
    __shared__ float pr[NA];      // max Npb = 512

    q[lane] = bf2f(qkv[(size_t)rowtok * 2304 + h * 64 + lane]);
    __syncthreads();

    const size_t kbase = ((size_t)b * Npb) * 2304 + DMODEL + h * 64;
    for (int n = lane; n < Npb; n += 64) {
        const uint4* kr = (const uint4*)(qkv + kbase + (size_t)n * 2304);
        float s = 0.f;
        #pragma unroll
        for (int w8 = 0; w8 < 8; w8++) {
            uint4 u = kr[w8];
            const float* qq = q + w8 * 8;
            s += qq[0] * bflo(u.x) + qq[1] * bfhi(u.x)
               + qq[2] * bflo(u.y) + qq[3] * bfhi(u.y)
               + qq[4] * bflo(u.z) + qq[5] * bfhi(u.z)
               + qq[6] * bflo(u.w) + qq[7] * bfhi(u.w);
        }
        pr[n] = s * 0.125f;  // 64^-0.5
    }
    __syncthreads();

    float mx = -1e30f;
    for (int n = lane; n < Npb; n += 64) mx = fmaxf(mx, pr[n]);
    #pragma unroll
    for (int off = 32; off; off >>= 1) mx = fmaxf(mx, __shfl_xor(mx, off));
    float den = 0.f;
    for (int n = lane; n < Npb; n += 64) { float e = __expf(pr[n] - mx); pr[n] = e; den += e; }
    #pragma unroll
    for (int off = 32; off; off >>= 1) den += __shfl_xor(den, off);
    __syncthreads();

    const size_t vbase = ((size_t)b * Npb) * 2304 + 2 * DMODEL + h * 64 + lane;
    float acc = 0.f;
    for (int n = 0; n < Npb; n++) acc += pr[n] * bf2f(qkv[vbase + (size_t)n * 2304]);
    st1(o + (size_t)rowtok * DMODEL + h * 64 + lane, acc / den);
}

// ---------------------------------------------------------------------------
// Tiled GEMM: C[M,N] = epi(A[M,K] @ W[N,K]^T + bias). A/resid bf16 ws,
// W/bias/scale raw inputs (TW), out TOut. ACT: 0 none, 1 exact GELU,
// 2 quickGELU. M%64==0, N%64==0, K%16==0 for all call sites.
// ---------------------------------------------------------------------------
template<typename TW, typename TOut, int ACT, bool RES, bool SCALE>
__global__ __launch_bounds__(256)
void gemm_kernel(const int* __restrict__ flag, int want,
                 const bf16* __restrict__ A, const TW* __restrict__ W,
                 const TW* __restrict__ bias, const bf16* __restrict__ resid,
                 const TW* __restrict__ scale_p, TOut* __restrict__ Cout,
                 int M, int N, int K)
{
    if (flag[0] != want) return;
    __shared__ float As[16][68];
    __shared__ float Ws[16][68];
    const int tid = threadIdx.x;
    const int tx = tid & 15, ty = tid >> 4;
    const int m0 = blockIdx.y * 64, n0 = blockIdx.x * 64;
    const int lr = tid >> 2;
    const int lk = (tid & 3) * 4;

    const bf16* Ap = A + (size_t)(m0 + lr) * K + lk;
    const TW* Wp = W + (size_t)(n0 + lr) * K + lk;

    float acc[4][4] = {};
    for (int k0 = 0; k0 < K; k0 += 16) {
        float4 av = ld4(Ap + k0);
        float4 wv = ld4(Wp + k0);
        As[lk + 0][lr] = av.x; As[lk + 1][lr] = av.y; As[lk + 2][lr] = av.z; As[lk + 3][lr] = av.w;
        Ws[lk + 0][lr] = wv.x; Ws[lk + 1][lr] = wv.y; Ws[lk + 2][lr] = wv.z; Ws[lk + 3][lr] = wv.w;
        __syncthreads();
        #pragma unroll
        for (int kk = 0; kk < 16; kk++) {
            float a[4], bb[4];
            #pragma unroll
            for (int i = 0; i < 4; i++) a[i] = As[kk][ty * 4 + i];
            #pragma unroll
            for (int j = 0; j < 4; j++) bb[j] = Ws[kk][tx * 4 + j];
            #pragma unroll
            for (int i = 0; i < 4; i++)
                #pragma unroll
                for (int j = 0; j < 4; j++) acc[i][j] += a[i] * bb[j];
        }
        __syncthreads();
    }

    const float sc = SCALE ? ld1(scale_p) : 1.0f;
    const int mb = m0 + ty * 4, nb = n0 + tx * 4;
    float bs[4];
    #pragma unroll
    for (int j = 0; j < 4; j++) bs[j] = ld1(bias + nb + j);
    #pragma unroll
    for (int i = 0; i < 4; i++) {
        const size_t rowoff = (size_t)(mb + i) * N + nb;
        #pragma unroll
        for (int j = 0; j < 4; j++) {
            float v = acc[i][j] + bs[j];
            if (ACT == 1) v = 0.5f * v * (1.0f + erff(v * 0.70710678118654752f));
            else if (ACT == 2) v = v / (1.0f + __expf(-1.702f * v));
            if (SCALE) v *= sc;
            if (RES) v += bf2f(resid[rowoff + j]);
            st1(Cout + rowoff + j, v);
        }
    }
}

// ---------------------------------------------------------------------------
// Host orchestration
// ---------------------------------------------------------------------------
struct SW {
    const void *ln1_g, *ln1_b, *qkv_w, *qkv_b, *proj_w, *proj_b,
               *ln2_g, *ln2_b, *fc1_w, *fc1_b, *fc2_w, *fc2_b,
               *down_w, *down_b, *up_w, *up_b, *scale;
};

template<typename TW, typename TOut>
static void run_stream_chunk(const int* flag, int want, const bf16* t0, int M, int Npb,
                             const SW& w, bf16* h, bf16* big, bf16* att, bf16* t1, bf16* ah,
                             TOut* out, hipStream_t s)
{
    ln_kernel<TW><<<M, 256, 0, s>>>(flag, want, t0, (const TW*)w.ln1_g, (const TW*)w.ln1_b, h);
    gemm_kernel<TW, bf16, 0, false, false><<<dim3(2304 / 64, M / 64), 256, 0, s>>>(
        flag, want, h, (const TW*)w.qkv_w, (const TW*)w.qkv_b, nullptr, nullptr, big, M, 2304, DMODEL);
    mhsa_attn_kernel<<<M * H_HEADS, 64, 0, s>>>(big, att, Npb);
    gemm_kernel<TW, bf16, 0, true, false><<<dim3(DMODEL / 64, M / 64), 256, 0, s>>>(
        flag, want, att, (const TW*)w.proj_w, (const TW*)w.proj_b, t0, nullptr, t1, M, DMODEL, DMODEL);
    ln_kernel<TW><<<M, 256, 0, s>>>(flag, want, t1, (const TW*)w.ln2_g, (const TW*)w.ln2_b, h);
    gemm_kernel<TW, bf16, 1, false, false><<<dim3(DFF / 64, M / 64), 256, 0, s>>>(
        flag, want, h, (const TW*)w.fc1_w, (const TW*)w.fc1_b, nullptr, nullptr, big, M, DFF, DMODEL);
    gemm_kernel<TW, bf16, 2, false, false><<<dim3(ADIM / 64, M / 64), 256, 0, s>>>(
        flag, want, h, (const TW*)w.down_w, (const TW*)w.down_b, nullptr, nullptr, ah, M, ADIM, DMODEL);
    gemm_kernel<TW, bf16, 0, true, false><<<dim3(DMODEL / 64, M / 64), 256, 0, s>>>(
        flag, want, big, (const TW*)w.fc2_w, (const TW*)w.fc2_b, t1, nullptr, att, M, DMODEL, DFF);
    gemm_kernel<TW, TOut, 0, true, true><<<dim3(DMODEL / 64, M / 64), 256, 0, s>>>(
        flag, want, ah, (const TW*)w.up_w, (const TW*)w.up_b, att, (const TW*)w.scale, out, M, DMODEL, ADIM);
}

extern "C" void kernel_launch(void* const* d_in, const int* in_sizes, int n_in,
                              void* d_out, int out_size, void* d_ws, size_t ws_size,
                              hipStream_t stream)
{
    SW sw, rw;
    auto fill = [&](SW& s, int base) {
        s.ln1_g = d_in[base + 0];  s.ln1_b = d_in[base + 1];
        s.qkv_w = d_in[base + 2];  s.qkv_b = d_in[base + 3];
        s.proj_w = d_in[base + 4]; s.proj_b = d_in[base + 5];
        s.ln2_g = d_in[base + 6];  s.ln2_b = d_in[base + 7];
        s.fc1_w = d_in[base + 8];  s.fc1_b = d_in[base + 9];
        s.fc2_w = d_in[base + 10]; s.fc2_b = d_in[base + 11];
        s.down_w = d_in[base + 12]; s.down_b = d_in[base + 13];
        s.up_w = d_in[base + 14];  s.up_b = d_in[base + 15];
        s.scale = d_in[base + 16];
    };
    fill(sw, 5);
    fill(rw, 22);

    const int Mx = BATCH * NA;   // 8192
    const int My = BATCH * NV;   // 3136
    const int MCH = 2048;        // x-stream chunk rows (4 batch items)

    // ws layout (bytes): flag 64 | fused f32 1.57M | x1 12.6M | y1 4.8M |
    // h 4.8M | big 19.3M | att 4.8M | t1 4.8M | ah 0.4M   (total ~53.1 MB)
    int* flag = (int*)d_ws;
    char* base = (char*)d_ws + 64;
    float* fused = (float*)base;              base += (size_t)BATCH * NLAT * DMODEL * 4;
    bf16* x1 = (bf16*)base;                   base += (size_t)Mx * DMODEL * 2;
    bf16* y1 = (bf16*)base;                   base += (size_t)My * DMODEL * 2;
    bf16* h  = (bf16*)base;                   base += (size_t)My * DMODEL * 2;   // max(MCH,My)=3136 rows
    bf16* big = (bf16*)base;                  base += (size_t)My * DFF * 2;
    bf16* att = (bf16*)base;                  base += (size_t)My * DMODEL * 2;
    bf16* t1  = (bf16*)base;                  base += (size_t)My * DMODEL * 2;
    bf16* ah  = (bf16*)base;                  base += (size_t)My * ADIM * 2;

    detect_dtype_kernel<<<1, 64, 0, stream>>>((const unsigned short*)d_in[0], flag);

    // --- fusion (dual-path) ---
    fusion_latents_kernel<bf16><<<BATCH * NLAT, 256, 0, stream>>>(
        flag, 0, (const bf16*)d_in[0], (const bf16*)d_in[1], (const bf16*)d_in[2], fused);
    fusion_latents_kernel<float><<<BATCH * NLAT, 256, 0, stream>>>(
        flag, 1, (const float*)d_in[0], (const float*)d_in[1], (const float*)d_in[2], fused);
    attend_fused_kernel<bf16><<<BATCH * NA, 256, 0, stream>>>(
        flag, 0, (const bf16*)d_in[0], fused, (const bf16*)d_in[3], x1, NA);
    attend_fused_kernel<float><<<BATCH * NA, 256, 0, stream>>>(
        flag, 1, (const float*)d_in[0], fused, (const float*)d_in[3], x1, NA);
    attend_fused_kernel<bf16><<<BATCH * NV, 256, 0, stream>>>(
        flag, 0, (const bf16*)d_in[1], fused, (const bf16*)d_in[4], y1, NV);
    attend_fused_kernel<float><<<BATCH * NV, 256, 0, stream>>>(
        flag, 1, (const float*)d_in[1], fused, (const float*)d_in[4], y1, NV);

    // --- x stream: 4 chunks of 2048 rows (whole batch items per chunk) ---
    for (int c = 0; c < 4; c++) {
        const bf16* t0 = x1 + (size_t)c * MCH * DMODEL;
        run_stream_chunk<bf16, bf16>(flag, 0, t0, MCH, NA, sw, h, big, att, t1, ah,
                                     (bf16*)d_out + (size_t)c * MCH * DMODEL, stream);
        run_stream_chunk<float, float>(flag, 1, t0, MCH, NA, sw, h, big, att, t1, ah,
                                       (float*)d_out + (size_t)c * MCH * DMODEL, stream);
    }
    // --- y stream: single pass (3136 rows) ---
    run_stream_chunk<bf16, bf16>(flag, 0, y1, My, NV, rw, h, big, att, t1, ah,
                                 (bf16*)d_out + (size_t)Mx * DMODEL, stream);
    run_stream_chunk<float, float>(flag, 1, y1, My, NV, rw, h, big, att, t1, ah,
                                   (float*)d_out + (size_t)Mx * DMODEL, stream);
}

// Round 3
// 1430.912 us; speedup vs baseline: 5.5769x; 5.5769x over previous
//
#include <hip/hip_runtime.h>
#include <hip/hip_bf16.h>

// AdaptFormer — Round 2: MFMA everywhere.
//  * bf16 16x16x32 MFMA GEMM (128x128 tile, BK=32, global_load_lds width=16,
//    XOR-swizzled LDS -> conflict-free ds_read_b128 frag loads)
//  * flash-style MFMA attention (replaces the 2.7ms scalar mhsa kernel)
//  * dtype branch folded inside kernels (no dead dispatches)
//  * unchunked x-stream when ws_size permits (82MB), else proven chunked layout

#define H_HEADS 12
#define DMODEL 768
#define DFF 3072
#define ADIM 64
#define NLAT 32
#define BATCH 16
#define NA 512
#define NV 196

typedef __hip_bfloat16 bf16;
using bf16x8 = __attribute__((ext_vector_type(8))) short;
using f32x4  = __attribute__((ext_vector_type(4))) float;

static __device__ __forceinline__ float bf2f(bf16 v) { return __bfloat162float(v); }
static __device__ __forceinline__ float bflo(unsigned u) { return __uint_as_float(u << 16); }
static __device__ __forceinline__ float bfhi(unsigned u) { return __uint_as_float(u & 0xffff0000u); }
static __device__ __forceinline__ float ld1(const float* p) { return *p; }
static __device__ __forceinline__ float ld1(const bf16* p) { return bf2f(*p); }
static __device__ __forceinline__ float4 ld4(const float* p) { return *(const float4*)p; }
static __device__ __forceinline__ float4 ld4(const bf16* p) {
    ushort4 u = *(const ushort4*)p;
    return make_float4(bflo(u.x), bflo(u.y), bflo(u.z), bflo(u.w));
}
static __device__ __forceinline__ unsigned short f2bf_bits(float v) {
    unsigned u = __float_as_uint(v);
    return (unsigned short)((u + 0x7fffu + ((u >> 16) & 1u)) >> 16);
}

#define GLD_LDS16(gp, lp) __builtin_amdgcn_global_load_lds( \
    (const __attribute__((address_space(1))) void*)(gp), \
    (__attribute__((address_space(3))) void*)(lp), 16, 0, 0)

// ---------------------------------------------------------------------------
// Dtype detector: 0 = inputs bf16, 1 = inputs f32 (bf16-view exponent census)
// ---------------------------------------------------------------------------
__global__ void detect_dtype_kernel(const unsigned short* __restrict__ x, int* __restrict__ flag)
{
    if (threadIdx.x == 0 && blockIdx.x == 0) {
        int big = 0;
        for (int i = 0; i < 2048; i++) {
            unsigned e = (x[i] >> 7) & 0xFF;
            if (e >= 0x90) big++;
        }
        flag[0] = (big > 16) ? 1 : 0;
    }
}

// ---------------------------------------------------------------------------
// Fusion stage 1 body
// ---------------------------------------------------------------------------
template<typename TIn>
static __device__ __forceinline__ void fusion_latents_body(
    const TIn* __restrict__ x, const TIn* __restrict__ y,
    const TIn* __restrict__ lat, float* __restrict__ fused)
{
    const int b = blockIdx.x >> 5;
    const int l = blockIdx.x & 31;
    const int tid = threadIdx.x;
    const int NTOT = NA + NV;

    __shared__ float q[DMODEL];
    __shared__ float sc[NA + NV];
    __shared__ float red[4];

    for (int d = tid; d < DMODEL; d += 256) q[d] = ld1(lat + l * DMODEL + d);
    __syncthreads();

    for (int n = tid; n < NTOT; n += 256) {
        const TIn* rowp = (n < NA)
            ? x + ((size_t)(b * NA + n)) * DMODEL
            : y + ((size_t)(b * NV + (n - NA))) * DMODEL;
        float s = 0.f;
        for (int d = 0; d < DMODEL; d += 4) {
            float4 rv = ld4(rowp + d);
            s += q[d] * rv.x + q[d + 1] * rv.y + q[d + 2] * rv.z + q[d + 3] * rv.w;
        }
        sc[n] = s * 0.03608439182435161f;
    }
    __syncthreads();

    float mx = -1e30f;
    for (int n = tid; n < NTOT; n += 256) mx = fmaxf(mx, sc[n]);
    #pragma unroll
    for (int off = 32; off; off >>= 1) mx = fmaxf(mx, __shfl_xor(mx, off));
    if ((tid & 63) == 0) red[tid >> 6] = mx;
    __syncthreads();
    mx = fmaxf(fmaxf(red[0], red[1]), fmaxf(red[2], red[3]));
    __syncthreads();
    float ds = 0.f;
    for (int n = tid; n < NTOT; n += 256) { float e = __expf(sc[n] - mx); sc[n] = e; ds += e; }
    #pragma unroll
    for (int off = 32; off; off >>= 1) ds += __shfl_xor(ds, off);
    __syncthreads();
    if ((tid & 63) == 0) red[tid >> 6] = ds;
    __syncthreads();
    const float inv = 1.0f / (red[0] + red[1] + red[2] + red[3]);

    float a0 = 0.f, a1 = 0.f, a2 = 0.f;
    for (int n = 0; n < NTOT; n++) {
        const TIn* rowp = (n < NA)
            ? x + ((size_t)(b * NA + n)) * DMODEL
            : y + ((size_t)(b * NV + (n - NA))) * DMODEL;
        const float pn = sc[n];
        a0 += pn * ld1(rowp + tid);
        a1 += pn * ld1(rowp + tid + 256);
        a2 += pn * ld1(rowp + tid + 512);
    }
    float* o = fused + (size_t)blockIdx.x * DMODEL;
    o[tid] = a0 * inv; o[tid + 256] = a1 * inv; o[tid + 512] = a2 * inv;
}

__global__ __launch_bounds__(256)
void fusion_latents_kernel(const int* __restrict__ flag, const void* x, const void* y,
                           const void* lat, float* __restrict__ fused)
{
    if (flag[0]) fusion_latents_body<float>((const float*)x, (const float*)y, (const float*)lat, fused);
    else         fusion_latents_body<bf16>((const bf16*)x, (const bf16*)y, (const bf16*)lat, fused);
}

// ---------------------------------------------------------------------------
// Fusion stage 2 body: out = t + scale * softmax(t.fused/sqrt(768)) @ fused
// ---------------------------------------------------------------------------
template<typename TIn>
static __device__ __forceinline__ void attend_fused_body(
    const TIn* __restrict__ t, const float* __restrict__ fused,
    const TIn* __restrict__ scale_p, bf16* __restrict__ out, int Npb)
{
    const int tid = threadIdx.x;
    const int gid = blockIdx.x;
    const int b = gid / Npb;
    const TIn* row = t + (size_t)gid * DMODEL;
    const float* fb = fused + (size_t)b * NLAT * DMODEL;

    __shared__ float q[DMODEL];
    __shared__ float p[NLAT];

    for (int d = tid; d < DMODEL; d += 256) q[d] = ld1(row + d);
    __syncthreads();

    const int g = tid >> 3, li = tid & 7;
    float s = 0.f;
    const float* fr = fb + (size_t)g * DMODEL;
    for (int d = li; d < DMODEL; d += 8) s += q[d] * fr[d];
    s += __shfl_xor(s, 1); s += __shfl_xor(s, 2); s += __shfl_xor(s, 4);
    if (li == 0) p[g] = s * 0.03608439182435161f;
    __syncthreads();

    float mx = -1e30f;
    #pragma unroll
    for (int l = 0; l < NLAT; l++) mx = fmaxf(mx, p[l]);
    float w[NLAT];
    float den = 0.f;
    #pragma unroll
    for (int l = 0; l < NLAT; l++) { w[l] = __expf(p[l] - mx); den += w[l]; }
    const float sA = ld1(scale_p) / den;

    float a0 = 0.f, a1 = 0.f, a2 = 0.f;
    #pragma unroll
    for (int l = 0; l < NLAT; l++) {
        const float* fv = fb + (size_t)l * DMODEL;
        a0 += w[l] * fv[tid];
        a1 += w[l] * fv[tid + 256];
        a2 += w[l] * fv[tid + 512];
    }
    bf16* o = out + (size_t)gid * DMODEL;
    o[tid]       = __float2bfloat16(q[tid]       + sA * a0);
    o[tid + 256] = __float2bfloat16(q[tid + 256] + sA * a1);
    o[tid + 512] = __float2bfloat16(q[tid + 512] + sA * a2);
}

__global__ __launch_bounds__(256)
void attend_fused_kernel(const int* __restrict__ flag, const void* t, const float* __restrict__ fused,
                         const void* scale_p, bf16* __restrict__ out, int Npb)
{
    if (flag[0]) attend_fused_body<float>((const float*)t, fused, (const float*)scale_p, out, Npb);
    else         attend_fused_body<bf16>((const bf16*)t, fused, (const bf16*)scale_p, out, Npb);
}

// ---------------------------------------------------------------------------
// LayerNorm body (bf16 ws in/out; gamma/beta raw input dtype)
// ---------------------------------------------------------------------------
template<typename TW>
static __device__ __forceinline__ void ln_body(
    const bf16* __restrict__ in, const TW* __restrict__ g,
    const TW* __restrict__ bta, bf16* __restrict__ out)
{
    const int tid = threadIdx.x;
    const bf16* p = in + (size_t)blockIdx.x * DMODEL;
    const float v0 = bf2f(p[tid]), v1 = bf2f(p[tid + 256]), v2 = bf2f(p[tid + 512]);
    float s = v0 + v1 + v2;
    float sq = v0 * v0 + v1 * v1 + v2 * v2;
    #pragma unroll
    for (int off = 32; off; off >>= 1) { s += __shfl_xor(s, off); sq += __shfl_xor(sq, off); }
    __shared__ float rs[4], rq[4];
    if ((tid & 63) == 0) { rs[tid >> 6] = s; rq[tid >> 6] = sq; }
    __syncthreads();
    s = rs[0] + rs[1] + rs[2] + rs[3];
    sq = rq[0] + rq[1] + rq[2] + rq[3];
    const float mean = s * (1.0f / DMODEL);
    const float var = sq * (1.0f / DMODEL) - mean * mean;
    const float r = rsqrtf(var + 1e-6f);
    bf16* o = out + (size_t)blockIdx.x * DMODEL;
    o[tid]       = __float2bfloat16((v0 - mean) * r * ld1(g + tid)       + ld1(bta + tid));
    o[tid + 256] = __float2bfloat16((v1 - mean) * r * ld1(g + tid + 256) + ld1(bta + tid + 256));
    o[tid + 512] = __float2bfloat16((v2 - mean) * r * ld1(g + tid + 512) + ld1(bta + tid + 512));
}

__global__ __launch_bounds__(256)
void ln_kernel(const int* __restrict__ flag, const bf16* __restrict__ in,
               const void* g, const void* b, bf16* __restrict__ out)
{
    if (flag[0]) ln_body<float>(in, (const float*)g, (const float*)b, out);
    else         ln_body<bf16>(in, (const bf16*)g, (const bf16*)b, out);
}

// ---------------------------------------------------------------------------
// Flash MFMA attention. qkv bf16 [nb*Npb, 2304] ([q|k|v] x h*64+d).
// o bf16 [nb*Npb, 768]. grid: (ceil(Npb/64), 12, nb) x 256 threads.
// Each wave owns 16 Q-rows; K staged async+swizzled; V staged transposed.
// ---------------------------------------------------------------------------
__global__ __launch_bounds__(256)
void flash_attn_kernel(const bf16* __restrict__ qkv, bf16* __restrict__ o, int Npb)
{
    const int tid = threadIdx.x;
    const int wv = tid >> 6, lane = tid & 63;
    const int l15 = lane & 15, q4 = lane >> 4;
    const int qt = blockIdx.x, h = blockIdx.y, bb = blockIdx.z;
    const int nkv = (Npb + 63) >> 6;
    const size_t tokbase = (size_t)bb * Npb;

    __shared__ __align__(16) short Ks[64 * 64];
    __shared__ __align__(16) short Vt[64 * 64];
    __shared__ __align__(16) short Ps[4][16 * 64];

    // Q fragments (A-layout: m=l15, k-chunk q4), rows clamped to Npb
    const int qr = min(qt * 64 + wv * 16 + l15, Npb - 1);
    const bf16* qp = qkv + (tokbase + qr) * 2304 + h * 64;
    const bf16x8 qf0 = *(const bf16x8*)(const void*)(qp + q4 * 8);
    const bf16x8 qf1 = *(const bf16x8*)(const void*)(qp + 32 + q4 * 8);

    f32x4 Oa[4] = {};
    float mrow[4], lrow[4];
    #pragma unroll
    for (int i = 0; i < 4; i++) { mrow[i] = -1e30f; lrow[i] = 0.f; }

    for (int kv = 0; kv < nkv; kv++) {
        const int kv0 = kv * 64;
        __syncthreads();
        // --- stage K tile [64 rows][8 chunks], swizzled: slot(row,pos) holds chunk pos^(row&7)
        #pragma unroll
        for (int inst = 0; inst < 2; inst++) {
            const int s = inst * 256 + tid;
            const int row = s >> 3, pos = s & 7;
            const int c = pos ^ (row & 7);
            const int krc = min(kv0 + row, Npb - 1);
            GLD_LDS16(qkv + (tokbase + krc) * 2304 + DMODEL + h * 64 + c * 8, &Ks[s * 8]);
        }
        // --- stage V transposed: Vt[feat][kvrow], chunk stored at pos = chunk^(feat&7)
        {
            const int r = tid >> 2;
            const int f0 = (tid & 3) * 16;
            const int krc = min(kv0 + r, Npb - 1);
            const short* vp = (const short*)(qkv + (tokbase + krc) * 2304 + 2 * DMODEL + h * 64 + f0);
            short vb[16];
            *(uint4*)&vb[0] = *(const uint4*)vp;
            *(uint4*)&vb[8] = *(const uint4*)(vp + 8);
            const int chunk = r >> 3, r7 = r & 7;
            #pragma unroll
            for (int j = 0; j < 16; j++) {
                const int feat = f0 + j;
                Vt[feat * 64 + (chunk ^ (feat & 7)) * 8 + r7] = vb[j];
            }
        }
        __syncthreads();

        // --- S = Q @ K^T  (16 q-rows x 64 kv-cols per wave)
        f32x4 s4[4] = {};
        #pragma unroll
        for (int kk = 0; kk < 2; kk++) {
            const bf16x8 qf = kk ? qf1 : qf0;
            const int c = kk * 4 + q4;
            #pragma unroll
            for (int g = 0; g < 4; g++) {
                const int r = g * 16 + l15;
                const bf16x8 kf = *(const bf16x8*)(const void*)&Ks[r * 64 + (c ^ (r & 7)) * 8];
                s4[g] = __builtin_amdgcn_mfma_f32_16x16x32_bf16(qf, kf, s4[g], 0, 0, 0);
            }
        }
        // --- online softmax (C-layout: col=g*16+l15, row=q4*4+i)
        float tmax[4];
        #pragma unroll
        for (int i = 0; i < 4; i++) tmax[i] = -1e30f;
        #pragma unroll
        for (int g = 0; g < 4; g++) {
            const bool valid = (kv0 + g * 16 + l15) < Npb;
            #pragma unroll
            for (int i = 0; i < 4; i++) {
                const float v = s4[g][i] * 0.125f;
                s4[g][i] = valid ? v : -1e30f;
                tmax[i] = fmaxf(tmax[i], s4[g][i]);
            }
        }
        #pragma unroll
        for (int off = 1; off < 16; off <<= 1)
            #pragma unroll
            for (int i = 0; i < 4; i++) tmax[i] = fmaxf(tmax[i], __shfl_xor(tmax[i], off));
        float alpha[4], rsum[4];
        #pragma unroll
        for (int i = 0; i < 4; i++) {
            const float mn = fmaxf(mrow[i], tmax[i]);
            alpha[i] = __expf(mrow[i] - mn);
            mrow[i] = mn;
            rsum[i] = 0.f;
        }
        #pragma unroll
        for (int g = 0; g < 4; g++) {
            const int cc = g * 16 + l15;
            const int chunk = cc >> 3;
            #pragma unroll
            for (int i = 0; i < 4; i++) {
                const int r = q4 * 4 + i;
                const float p = __expf(s4[g][i] - mrow[i]);  // masked lanes: exp(-1e30-m)=0
                rsum[i] += p;
                Ps[wv][r * 64 + (chunk ^ (r & 7)) * 8 + (cc & 7)] = (short)f2bf_bits(p);
            }
        }
        #pragma unroll
        for (int off = 1; off < 16; off <<= 1)
            #pragma unroll
            for (int i = 0; i < 4; i++) rsum[i] += __shfl_xor(rsum[i], off);
        #pragma unroll
        for (int i = 0; i < 4; i++) lrow[i] = lrow[i] * alpha[i] + rsum[i];
        #pragma unroll
        for (int g = 0; g < 4; g++)
            #pragma unroll
            for (int i = 0; i < 4; i++) Oa[g][i] *= alpha[i];

        // --- O += P @ V   (P A-frags from wave-private LDS; Vt B-frags)
        #pragma unroll
        for (int kk = 0; kk < 2; kk++) {
            const int c = kk * 4 + q4;
            const bf16x8 pf = *(const bf16x8*)(const void*)&Ps[wv][l15 * 64 + (c ^ (l15 & 7)) * 8];
            #pragma unroll
            for (int g = 0; g < 4; g++) {
                const int feat = g * 16 + l15;
                const bf16x8 vf = *(const bf16x8*)(const void*)&Vt[feat * 64 + (c ^ (feat & 7)) * 8];
                Oa[g] = __builtin_amdgcn_mfma_f32_16x16x32_bf16(pf, vf, Oa[g], 0, 0, 0);
            }
        }
    }

    float inv[4];
    #pragma unroll
    for (int i = 0; i < 4; i++) inv[i] = 1.0f / lrow[i];
    #pragma unroll
    for (int g = 0; g < 4; g++) {
        const int colo = h * 64 + g * 16 + l15;
        #pragma unroll
        for (int i = 0; i < 4; i++) {
            const int rowg = qt * 64 + wv * 16 + q4 * 4 + i;
            if (rowg < Npb)
                o[(tokbase + rowg) * DMODEL + colo] = __float2bfloat16(Oa[g][i] * inv[i]);
        }
    }
}

// ---------------------------------------------------------------------------
// MFMA GEMM: C[M,N] = epi(A[M,K] @ W[N,K]^T + bias). A/resid bf16 ws,
// W/bias/scale raw dtype TW. 128x128 tile, BK=32, swizzled LDS.
// ACT: 0 none, 1 exact GELU, 2 quickGELU.
// ---------------------------------------------------------------------------
template<typename TW, int ACT, bool RES, bool SCALE>
static __device__ __forceinline__ void gemm_body(
    const bf16* __restrict__ A, const TW* __restrict__ W, const TW* __restrict__ bias,
    const bf16* __restrict__ resid, const TW* __restrict__ scale_p, void* __restrict__ C,
    bool cf32, int row_off, int M, int N, int K, short* As, short* Bs)
{
    const int tid = threadIdx.x;
    const int lane = tid & 63;
    const int wv = tid >> 6;
    const int l15 = lane & 15, q4 = lane >> 4;
    const int m0 = blockIdx.y * 128, n0 = blockIdx.x * 128;
    const int wm = (wv & 1) * 64, wn = (wv >> 1) * 64;

    f32x4 acc[4][4] = {};

    for (int k0 = 0; k0 < K; k0 += 32) {
        __syncthreads();
        #pragma unroll
        for (int inst = 0; inst < 2; inst++) {
            const int s = inst * 256 + tid;
            const int row = s >> 2, pos = s & 3;
            const int c = pos ^ ((row >> 1) & 3);
            const int ra = min(m0 + row, M - 1);
            const int rb = min(n0 + row, N - 1);
            GLD_LDS16(A + (size_t)ra * K + k0 + c * 8, &As[s * 8]);
            if (sizeof(TW) == 2) {
                GLD_LDS16((const bf16*)W + (size_t)rb * K + k0 + c * 8, &Bs[s * 8]);
            } else {
                const float* wp = (const float*)W + (size_t)rb * K + k0 + c * 8;
                const float4 w0 = *(const float4*)wp;
                const float4 w1 = *(const float4*)(wp + 4);
                unsigned short hb[8];
                hb[0] = f2bf_bits(w0.x); hb[1] = f2bf_bits(w0.y);
                hb[2] = f2bf_bits(w0.z); hb[3] = f2bf_bits(w0.w);
                hb[4] = f2bf_bits(w1.x); hb[5] = f2bf_bits(w1.y);
                hb[6] = f2bf_bits(w1.z); hb[7] = f2bf_bits(w1.w);
                *(uint4*)&Bs[s * 8] = *(const uint4*)hb;
            }
        }
        __syncthreads();

        bf16x8 af[4], bfr[4];
        #pragma unroll
        for (int f = 0; f < 4; f++) {
            const int r = wm + f * 16 + l15;
            af[f] = *(const bf16x8*)(const void*)&As[r * 32 + (q4 ^ ((r >> 1) & 3)) * 8];
            const int rn = wn + f * 16 + l15;
            bfr[f] = *(const bf16x8*)(const void*)&Bs[rn * 32 + (q4 ^ ((rn >> 1) & 3)) * 8];
        }
        #pragma unroll
        for (int f = 0; f < 4; f++)
            #pragma unroll
            for (int g = 0; g < 4; g++)
                acc[f][g] = __builtin_amdgcn_mfma_f32_16x16x32_bf16(af[f], bfr[g], acc[f][g], 0, 0, 0);
    }

    const float sc = SCALE ? ld1(scale_p) : 1.0f;
    #pragma unroll
    for (int g = 0; g < 4; g++) {
        const int colg = n0 + wn + g * 16 + l15;
        if (colg >= N) continue;
        const float bv = ld1(bias + colg);
        #pragma unroll
        for (int f = 0; f < 4; f++) {
            const int rowb = m0 + wm + f * 16 + q4 * 4;
            #pragma unroll
            for (int i = 0; i < 4; i++) {
                const int rowg = rowb + i;
                if (rowg >= M) continue;
                float v = acc[f][g][i] + bv;
                if (ACT == 1) v = 0.5f * v * (1.0f + erff(v * 0.70710678118654752f));
                else if (ACT == 2) v = v / (1.0f + __expf(-1.702f * v));
                if (SCALE) v *= sc;
                const size_t idx = (size_t)rowg * N + colg;
                if (RES) v += bf2f(resid[idx]);
                const size_t sidx = (size_t)(rowg + row_off) * N + colg;
                if (cf32) ((float*)C)[sidx] = v;
                else ((bf16*)C)[sidx] = __float2bfloat16(v);
            }
        }
    }
}

template<int ACT, bool RES, bool SCALE>
__global__ __launch_bounds__(256)
void mfma_gemm_kernel(const int* __restrict__ flag, const bf16* __restrict__ A,
                      const void* __restrict__ W, const void* __restrict__ bias,
                      const bf16* __restrict__ resid, const void* __restrict__ sp,
                      void* __restrict__ C, int final_out, int row_off, int M, int N, int K)
{
    __shared__ __align__(16) short As[128 * 32];
    __shared__ __align__(16) short Bs[128 * 32];
    if (flag[0])
        gemm_body<float, ACT, RES, SCALE>(A, (const float*)W, (const float*)bias, resid,
                                          (const float*)sp, C, final_out != 0, row_off, M, N, K, As, Bs);
    else
        gemm_body<bf16, ACT, RES, SCALE>(A, (const bf16*)W, (const bf16*)bias, resid,
                                         (const bf16*)sp, C, false, row_off, M, N, K, As, Bs);
}

// ---------------------------------------------------------------------------
// Host orchestration
// ---------------------------------------------------------------------------
struct SW {
    const void *ln1_g, *ln1_b, *qkv_w, *qkv_b, *proj_w, *proj_b,
               *ln2_g, *ln2_b, *fc1_w, *fc1_b, *fc2_w, *fc2_b,
               *down_w, *down_b, *up_w, *up_b, *scale;
};

static void run_stream(const int* flag, bf16* t0, int M, int Npb, int nb, const SW& w,
                       bf16* h, bf16* big, bf16* ah, void* out, int out_row_off, hipStream_t s)
{
    const dim3 g768((DMODEL + 127) / 128, (M + 127) / 128);
    const dim3 g2304((2304 + 127) / 128, (M + 127) / 128);
    const dim3 g3072((DFF + 127) / 128, (M + 127) / 128);
    const dim3 g64((ADIM + 127) / 128, (M + 127) / 128);

    // h = LN1(t0); big = qkv
    ln_kernel<<<M, 256, 0, s>>>(flag, t0, w.ln1_g, w.ln1_b, h);
    mfma_gemm_kernel<0, false, false><<<g2304, 256, 0, s>>>(
        flag, h, w.qkv_w, w.qkv_b, nullptr, nullptr, big, 0, 0, M, 2304, DMODEL);
    // attn -> h (reuse)
    flash_attn_kernel<<<dim3((Npb + 63) / 64, H_HEADS, nb), 256, 0, s>>>(big, h, Npb);
    // t0 += proj(h)   (in place)
    mfma_gemm_kernel<0, true, false><<<g768, 256, 0, s>>>(
        flag, h, w.proj_w, w.proj_b, t0, nullptr, t0, 0, 0, M, DMODEL, DMODEL);
    // h = LN2(t0)
    ln_kernel<<<M, 256, 0, s>>>(flag, t0, w.ln2_g, w.ln2_b, h);
    // big = gelu(fc1(h)); ah = qgelu(down(h))
    mfma_gemm_kernel<1, false, false><<<g3072, 256, 0, s>>>(
        flag, h, w.fc1_w, w.fc1_b, nullptr, nullptr, big, 0, 0, M, DFF, DMODEL);
    mfma_gemm_kernel<2, false, false><<<g64, 256, 0, s>>>(
        flag, h, w.down_w, w.down_b, nullptr, nullptr, ah, 0, 0, M, ADIM, DMODEL);
    // t0 += fc2(big)  (in place)
    mfma_gemm_kernel<0, true, false><<<g768, 256, 0, s>>>(
        flag, big, w.fc2_w, w.fc2_b, t0, nullptr, t0, 0, 0, M, DMODEL, DFF);
    // out = t0 + scale*up(ah)
    mfma_gemm_kernel<0, true, true><<<g768, 256, 0, s>>>(
        flag, ah, w.up_w, w.up_b, t0, w.scale, out, 1, out_row_off, M, DMODEL, ADIM);
}

extern "C" void kernel_launch(void* const* d_in, const int* in_sizes, int n_in,
                              void* d_out, int out_size, void* d_ws, size_t ws_size,
                              hipStream_t stream)
{
    SW sw, rw;
    auto fill = [&](SW& s, int base) {
        s.ln1_g = d_in[base + 0];  s.ln1_b = d_in[base + 1];
        s.qkv_w = d_in[base + 2];  s.qkv_b = d_in[base + 3];
        s.proj_w = d_in[base + 4]; s.proj_b = d_in[base + 5];
        s.ln2_g = d_in[base + 6];  s.ln2_b = d_in[base + 7];
        s.fc1_w = d_in[base + 8];  s.fc1_b = d_in[base + 9];
        s.fc2_w = d_in[base + 10]; s.fc2_b = d_in[base + 11];
        s.down_w = d_in[base + 12]; s.down_b = d_in[base + 13];
        s.up_w = d_in[base + 14];  s.up_b = d_in[base + 15];
        s.scale = d_in[base + 16];
    };
    fill(sw, 5);
    fill(rw, 22);

    const int Mx = BATCH * NA;   // 8192
    const int My = BATCH * NV;   // 3136

    // workspace layout; unchunked x needs ~82MB, chunked fallback ~43.5MB
    const size_t need_big = 256 + 1572864ull + (size_t)Mx * DMODEL * 2 + (size_t)My * DMODEL * 2
                          + (size_t)Mx * DMODEL * 2 + (size_t)Mx * DFF * 2 + (size_t)Mx * ADIM * 2;
    const bool big_ws = ws_size >= need_big;
    const int hrows = big_ws ? Mx : My;     // h / big / ah row capacity (y is never chunked)

    int* flag = (int*)d_ws;
    char* base = (char*)d_ws + 256;
    float* fused = (float*)base;              base += (size_t)BATCH * NLAT * DMODEL * 4;
    bf16* x1 = (bf16*)base;                   base += (size_t)Mx * DMODEL * 2;
    bf16* y1 = (bf16*)base;                   base += (size_t)My * DMODEL * 2;
    bf16* h  = (bf16*)base;                   base += (size_t)hrows * DMODEL * 2;
    bf16* big = (bf16*)base;                  base += (size_t)hrows * DFF * 2;
    bf16* ah = (bf16*)base;

    detect_dtype_kernel<<<1, 64, 0, stream>>>((const unsigned short*)d_in[0], flag);

    // --- fusion ---
    fusion_latents_kernel<<<BATCH * NLAT, 256, 0, stream>>>(flag, d_in[0], d_in[1], d_in[2], fused);
    attend_fused_kernel<<<BATCH * NA, 256, 0, stream>>>(flag, d_in[0], fused, d_in[3], x1, NA);
    attend_fused_kernel<<<BATCH * NV, 256, 0, stream>>>(flag, d_in[1], fused, d_in[4], y1, NV);

    // --- transformer streams ---
    if (big_ws) {
        run_stream(flag, x1, Mx, NA, BATCH, sw, h, big, ah, d_out, 0, stream);
    } else {
        const int MCH = 2048;  // 4 batch items per chunk
        for (int c = 0; c < Mx / MCH; c++)
            run_stream(flag, x1 + (size_t)c * MCH * DMODEL, MCH, NA, MCH / NA, sw,
                       h, big, ah, d_out, c * MCH, stream);
    }
    run_stream(flag, y1, My, NV, BATCH, rw, h, big, ah, d_out, Mx, stream);
}

// Round 4
// 1292.709 us; speedup vs baseline: 6.1731x; 1.1069x over previous
//
#include <hip/hip_runtime.h>
#include <hip/hip_bf16.h>

// AdaptFormer — Round 3: fusion stage rebuilt as GEMM pipeline.
//  * fusion_latents (208us, 512 redundant GEMVs, 273MB fetch) replaced by:
//    pack(concat->bf16) -> MFMA scores GEMM -> softmax -> d-tiled wsum (~35us)
//  * fused now bf16 -> attend_fused reads half the bytes
//  * GEMM gains nullable bias + out_mode (bf16 / follow-dtype / f32)

#define H_HEADS 12
#define DMODEL 768
#define DFF 3072
#define ADIM 64
#define NLAT 32
#define BATCH 16
#define NA 512
#define NV 196
#define NTOT 708          // NA + NV
#define MCAT (BATCH * NTOT)  // 11328

typedef __hip_bfloat16 bf16;
using bf16x8 = __attribute__((ext_vector_type(8))) short;
using f32x4  = __attribute__((ext_vector_type(4))) float;

static __device__ __forceinline__ float bf2f(bf16 v) { return __bfloat162float(v); }
static __device__ __forceinline__ float bflo(unsigned u) { return __uint_as_float(u << 16); }
static __device__ __forceinline__ float ld1(const float* p) { return *p; }
static __device__ __forceinline__ float ld1(const bf16* p) { return bf2f(*p); }
static __device__ __forceinline__ unsigned short f2bf_bits(float v) {
    unsigned u = __float_as_uint(v);
    return (unsigned short)((u + 0x7fffu + ((u >> 16) & 1u)) >> 16);
}

#define GLD_LDS16(gp, lp) __builtin_amdgcn_global_load_lds( \
    (const __attribute__((address_space(1))) void*)(gp), \
    (__attribute__((address_space(3))) void*)(lp), 16, 0, 0)

// ---------------------------------------------------------------------------
// Dtype detector: flag[0]=0 bf16 inputs, 1 f32. flag[1] stays 0 (used as an
// "always-bf16" flag for ws-sourced GEMMs).
// ---------------------------------------------------------------------------
__global__ void detect_dtype_kernel(const unsigned short* __restrict__ x, int* __restrict__ flag)
{
    if (threadIdx.x == 0 && blockIdx.x == 0) {
        int big = 0;
        for (int i = 0; i < 2048; i++) {
            unsigned e = (x[i] >> 7) & 0xFF;
            if (e >= 0x90) big++;
        }
        flag[0] = (big > 16) ? 1 : 0;
        flag[1] = 0;
    }
}

// ---------------------------------------------------------------------------
// Pack concat -> Cc bf16 [MCAT,768]; latents -> Lb bf16 [32,768]
// grid: MCAT + 32 blocks x 256
// ---------------------------------------------------------------------------
template<typename TIn>
static __device__ __forceinline__ void pack_body(
    const TIn* __restrict__ x, const TIn* __restrict__ y, const TIn* __restrict__ lat,
    bf16* __restrict__ Cc, bf16* __restrict__ Lb)
{
    const int r = blockIdx.x, tid = threadIdx.x;
    const TIn* src;
    bf16* dst;
    if (r < MCAT) {
        const int b = r / NTOT, n = r - b * NTOT;
        src = (n < NA) ? x + ((size_t)(b * NA + n)) * DMODEL
                       : y + ((size_t)(b * NV + (n - NA))) * DMODEL;
        dst = Cc + (size_t)r * DMODEL;
    } else {
        src = lat + (size_t)(r - MCAT) * DMODEL;
        dst = Lb + (size_t)(r - MCAT) * DMODEL;
    }
    dst[tid]       = __float2bfloat16(ld1(src + tid));
    dst[tid + 256] = __float2bfloat16(ld1(src + tid + 256));
    dst[tid + 512] = __float2bfloat16(ld1(src + tid + 512));
}

__global__ __launch_bounds__(256)
void pack_concat_kernel(const int* __restrict__ flag, const void* x, const void* y,
                        const void* lat, bf16* __restrict__ Cc, bf16* __restrict__ Lb)
{
    if (flag[0]) pack_body<float>((const float*)x, (const float*)y, (const float*)lat, Cc, Lb);
    else         pack_body<bf16>((const bf16*)x, (const bf16*)y, (const bf16*)lat, Cc, Lb);
}

// ---------------------------------------------------------------------------
// Fusion softmax: P[b][l][n] = softmax_n(scores[b*708+n][l] * 768^-0.5),
// rows padded with zeros to 768. grid: 512 blocks x 64
// ---------------------------------------------------------------------------
__global__ __launch_bounds__(64)
void fusion_softmax_kernel(const float* __restrict__ scores, float* __restrict__ P)
{
    const int b = blockIdx.x >> 5, l = blockIdx.x & 31, lane = threadIdx.x;
    const float* sp = scores + (size_t)b * NTOT * NLAT + l;
    float v[12];
    float mx = -1e30f;
    #pragma unroll
    for (int i = 0; i < 12; i++) {
        const int n = lane + i * 64;
        v[i] = (n < NTOT) ? sp[(size_t)n * NLAT] * 0.03608439182435161f : -1e30f;
        mx = fmaxf(mx, v[i]);
    }
    #pragma unroll
    for (int off = 32; off; off >>= 1) mx = fmaxf(mx, __shfl_xor(mx, off));
    float den = 0.f;
    #pragma unroll
    for (int i = 0; i < 12; i++) { v[i] = __expf(v[i] - mx); den += v[i]; }  // pads: exp(-inf)=0
    #pragma unroll
    for (int off = 32; off; off >>= 1) den += __shfl_xor(den, off);
    const float inv = 1.0f / den;
    float* op = P + ((size_t)b * NLAT + l) * 768;
    #pragma unroll
    for (int i = 0; i < 12; i++) {
        const int n = lane + i * 64;
        op[n] = (n < NTOT) ? v[i] * inv : 0.f;
    }
}

// ---------------------------------------------------------------------------
// Weighted sum: fused[b][l][d] = sum_n P[b][l][n] * Cc[b*708+n][d], bf16 out.
// grid: (6 d-tiles, 16 b) x 256. Each block owns a 128-wide d-slice -> concat
// read exactly once across the grid.
// ---------------------------------------------------------------------------
__global__ __launch_bounds__(256)
void fusion_wsum_kernel(const bf16* __restrict__ Cc, const float* __restrict__ P,
                        bf16* __restrict__ fused)
{
    const int b = blockIdx.y, d0 = blockIdx.x * 128;
    const int tid = threadIdx.x;
    const int lg = tid >> 5, dg = tid & 31;   // l-group (8), d-group (32)
    const int l0 = lg * 4;

    __shared__ float Ct[64][132];
    __shared__ float Ps[32][68];

    float acc[4][4] = {};

    for (int nc = 0; nc < 12; nc++) {
        const int n0 = nc * 64;
        __syncthreads();
        // stage Ct[r][c] = Cc[b*708 + n0 + r][d0 + c] (zeros past 708)
        #pragma unroll
        for (int it = 0; it < 8; it++) {
            const int idx = it * 1024 + tid * 4;
            const int r = idx >> 7, c = idx & 127;
            const int gn = n0 + r;
            float4 v = make_float4(0.f, 0.f, 0.f, 0.f);
            if (gn < NTOT) {
                const ushort4 u = *(const ushort4*)(Cc + ((size_t)(b * NTOT + gn)) * DMODEL + d0 + c);
                v = make_float4(bflo(u.x), bflo(u.y), bflo(u.z), bflo(u.w));
            }
            Ct[r][c] = v.x; Ct[r][c + 1] = v.y; Ct[r][c + 2] = v.z; Ct[r][c + 3] = v.w;
        }
        // stage Ps[l][j] = P[b][l][n0+j] (768-padded -> unguarded float4)
        {
            const int l = tid >> 3, off = (tid & 7) * 8;
            const float* pp = P + ((size_t)b * NLAT + l) * 768 + n0 + off;
            const float4 p0 = *(const float4*)pp;
            const float4 p1 = *(const float4*)(pp + 4);
            Ps[l][off] = p0.x; Ps[l][off + 1] = p0.y; Ps[l][off + 2] = p0.z; Ps[l][off + 3] = p0.w;
            Ps[l][off + 4] = p1.x; Ps[l][off + 5] = p1.y; Ps[l][off + 6] = p1.z; Ps[l][off + 7] = p1.w;
        }
        __syncthreads();

        for (int n = 0; n < 64; n++) {
            const float4 v = *(const float4*)&Ct[n][dg * 4];
            #pragma unroll
            for (int i = 0; i < 4; i++) {
                const float p = Ps[l0 + i][n];
                acc[i][0] += p * v.x; acc[i][1] += p * v.y;
                acc[i][2] += p * v.z; acc[i][3] += p * v.w;
            }
        }
    }

    #pragma unroll
    for (int i = 0; i < 4; i++) {
        bf16* op = fused + ((size_t)b * NLAT + l0 + i) * DMODEL + d0 + dg * 4;
        #pragma unroll
        for (int j = 0; j < 4; j++) op[j] = __float2bfloat16(acc[i][j]);
    }
}

// ---------------------------------------------------------------------------
// Fusion stage 2: out = t + scale * softmax(t.fused/sqrt(768)) @ fused
// fused is now bf16 [b][32][768].
// ---------------------------------------------------------------------------
template<typename TIn>
static __device__ __forceinline__ void attend_fused_body(
    const TIn* __restrict__ t, const bf16* __restrict__ fused,
    const TIn* __restrict__ scale_p, bf16* __restrict__ out, int Npb)
{
    const int tid = threadIdx.x;
    const int gid = blockIdx.x;
    const int b = gid / Npb;
    const TIn* row = t + (size_t)gid * DMODEL;
    const bf16* fb = fused + (size_t)b * NLAT * DMODEL;

    __shared__ float q[DMODEL];
    __shared__ float p[NLAT];

    for (int d = tid; d < DMODEL; d += 256) q[d] = ld1(row + d);
    __syncthreads();

    const int g = tid >> 3, li = tid & 7;
    float s = 0.f;
    const bf16* fr = fb + (size_t)g * DMODEL;
    for (int d = li; d < DMODEL; d += 8) s += q[d] * bf2f(fr[d]);
    s += __shfl_xor(s, 1); s += __shfl_xor(s, 2); s += __shfl_xor(s, 4);
    if (li == 0) p[g] = s * 0.03608439182435161f;
    __syncthreads();

    float mx = -1e30f;
    #pragma unroll
    for (int l = 0; l < NLAT; l++) mx = fmaxf(mx, p[l]);
    float w[NLAT];
    float den = 0.f;
    #pragma unroll
    for (int l = 0; l < NLAT; l++) { w[l] = __expf(p[l] - mx); den += w[l]; }
    const float sA = ld1(scale_p) / den;

    float a0 = 0.f, a1 = 0.f, a2 = 0.f;
    #pragma unroll
    for (int l = 0; l < NLAT; l++) {
        const bf16* fv = fb + (size_t)l * DMODEL;
        a0 += w[l] * bf2f(fv[tid]);
        a1 += w[l] * bf2f(fv[tid + 256]);
        a2 += w[l] * bf2f(fv[tid + 512]);
    }
    bf16* o = out + (size_t)gid * DMODEL;
    o[tid]       = __float2bfloat16(q[tid]       + sA * a0);
    o[tid + 256] = __float2bfloat16(q[tid + 256] + sA * a1);
    o[tid + 512] = __float2bfloat16(q[tid + 512] + sA * a2);
}

__global__ __launch_bounds__(256)
void attend_fused_kernel(const int* __restrict__ flag, const void* t, const bf16* __restrict__ fused,
                         const void* scale_p, bf16* __restrict__ out, int Npb)
{
    if (flag[0]) attend_fused_body<float>((const float*)t, fused, (const float*)scale_p, out, Npb);
    else         attend_fused_body<bf16>((const bf16*)t, fused, (const bf16*)scale_p, out, Npb);
}

// ---------------------------------------------------------------------------
// LayerNorm (bf16 ws in/out; gamma/beta raw input dtype)
// ---------------------------------------------------------------------------
template<typename TW>
static __device__ __forceinline__ void ln_body(
    const bf16* __restrict__ in, const TW* __restrict__ g,
    const TW* __restrict__ bta, bf16* __restrict__ out)
{
    const int tid = threadIdx.x;
    const bf16* p = in + (size_t)blockIdx.x * DMODEL;
    const float v0 = bf2f(p[tid]), v1 = bf2f(p[tid + 256]), v2 = bf2f(p[tid + 512]);
    float s = v0 + v1 + v2;
    float sq = v0 * v0 + v1 * v1 + v2 * v2;
    #pragma unroll
    for (int off = 32; off; off >>= 1) { s += __shfl_xor(s, off); sq += __shfl_xor(sq, off); }
    __shared__ float rs[4], rq[4];
    if ((tid & 63) == 0) { rs[tid >> 6] = s; rq[tid >> 6] = sq; }
    __syncthreads();
    s = rs[0] + rs[1] + rs[2] + rs[3];
    sq = rq[0] + rq[1] + rq[2] + rq[3];
    const float mean = s * (1.0f / DMODEL);
    const float var = sq * (1.0f / DMODEL) - mean * mean;
    const float r = rsqrtf(var + 1e-6f);
    bf16* o = out + (size_t)blockIdx.x * DMODEL;
    o[tid]       = __float2bfloat16((v0 - mean) * r * ld1(g + tid)       + ld1(bta + tid));
    o[tid + 256] = __float2bfloat16((v1 - mean) * r * ld1(g + tid + 256) + ld1(bta + tid + 256));
    o[tid + 512] = __float2bfloat16((v2 - mean) * r * ld1(g + tid + 512) + ld1(bta + tid + 512));
}

__global__ __launch_bounds__(256)
void ln_kernel(const int* __restrict__ flag, const bf16* __restrict__ in,
               const void* g, const void* b, bf16* __restrict__ out)
{
    if (flag[0]) ln_body<float>(in, (const float*)g, (const float*)b, out);
    else         ln_body<bf16>(in, (const bf16*)g, (const bf16*)b, out);
}

// ---------------------------------------------------------------------------
// Flash MFMA attention (unchanged from R2 — verified)
// ---------------------------------------------------------------------------
__global__ __launch_bounds__(256)
void flash_attn_kernel(const bf16* __restrict__ qkv, bf16* __restrict__ o, int Npb)
{
    const int tid = threadIdx.x;
    const int wv = tid >> 6, lane = tid & 63;
    const int l15 = lane & 15, q4 = lane >> 4;
    const int qt = blockIdx.x, h = blockIdx.y, bb = blockIdx.z;
    const int nkv = (Npb + 63) >> 6;
    const size_t tokbase = (size_t)bb * Npb;

    __shared__ __align__(16) short Ks[64 * 64];
    __shared__ __align__(16) short Vt[64 * 64];
    __shared__ __align__(16) short Ps[4][16 * 64];

    const int qr = min(qt * 64 + wv * 16 + l15, Npb - 1);
    const bf16* qp = qkv + (tokbase + qr) * 2304 + h * 64;
    const bf16x8 qf0 = *(const bf16x8*)(const void*)(qp + q4 * 8);
    const bf16x8 qf1 = *(const bf16x8*)(const void*)(qp + 32 + q4 * 8);

    f32x4 Oa[4] = {};
    float mrow[4], lrow[4];
    #pragma unroll
    for (int i = 0; i < 4; i++) { mrow[i] = -1e30f; lrow[i] = 0.f; }

    for (int kv = 0; kv < nkv; kv++) {
        const int kv0 = kv * 64;
        __syncthreads();
        #pragma unroll
        for (int inst = 0; inst < 2; inst++) {
            const int s = inst * 256 + tid;
            const int row = s >> 3, pos = s & 7;
            const int c = pos ^ (row & 7);
            const int krc = min(kv0 + row, Npb - 1);
            GLD_LDS16(qkv + (tokbase + krc) * 2304 + DMODEL + h * 64 + c * 8, &Ks[s * 8]);
        }
        {
            const int r = tid >> 2;
            const int f0 = (tid & 3) * 16;
            const int krc = min(kv0 + r, Npb - 1);
            const short* vp = (const short*)(qkv + (tokbase + krc) * 2304 + 2 * DMODEL + h * 64 + f0);
            short vb[16];
            *(uint4*)&vb[0] = *(const uint4*)vp;
            *(uint4*)&vb[8] = *(const uint4*)(vp + 8);
            const int chunk = r >> 3, r7 = r & 7;
            #pragma unroll
            for (int j = 0; j < 16; j++) {
                const int feat = f0 + j;
                Vt[feat * 64 + (chunk ^ (feat & 7)) * 8 + r7] = vb[j];
            }
        }
        __syncthreads();

        f32x4 s4[4] = {};
        #pragma unroll
        for (int kk = 0; kk < 2; kk++) {
            const bf16x8 qf = kk ? qf1 : qf0;
            const int c = kk * 4 + q4;
            #pragma unroll
            for (int g = 0; g < 4; g++) {
                const int r = g * 16 + l15;
                const bf16x8 kf = *(const bf16x8*)(const void*)&Ks[r * 64 + (c ^ (r & 7)) * 8];
                s4[g] = __builtin_amdgcn_mfma_f32_16x16x32_bf16(qf, kf, s4[g], 0, 0, 0);
            }
        }
        float tmax[4];
        #pragma unroll
        for (int i = 0; i < 4; i++) tmax[i] = -1e30f;
        #pragma unroll
        for (int g = 0; g < 4; g++) {
            const bool valid = (kv0 + g * 16 + l15) < Npb;
            #pragma unroll
            for (int i = 0; i < 4; i++) {
                const float v = s4[g][i] * 0.125f;
                s4[g][i] = valid ? v : -1e30f;
                tmax[i] = fmaxf(tmax[i], s4[g][i]);
            }
        }
        #pragma unroll
        for (int off = 1; off < 16; off <<= 1)
            #pragma unroll
            for (int i = 0; i < 4; i++) tmax[i] = fmaxf(tmax[i], __shfl_xor(tmax[i], off));
        float alpha[4], rsum[4];
        #pragma unroll
        for (int i = 0; i < 4; i++) {
            const float mn = fmaxf(mrow[i], tmax[i]);
            alpha[i] = __expf(mrow[i] - mn);
            mrow[i] = mn;
            rsum[i] = 0.f;
        }
        #pragma unroll
        for (int g = 0; g < 4; g++) {
            const int cc = g * 16 + l15;
            const int chunk = cc >> 3;
            #pragma unroll
            for (int i = 0; i < 4; i++) {
                const int r = q4 * 4 + i;
                const float p = __expf(s4[g][i] - mrow[i]);
                rsum[i] += p;
                Ps[wv][r * 64 + (chunk ^ (r & 7)) * 8 + (cc & 7)] = (short)f2bf_bits(p);
            }
        }
        #pragma unroll
        for (int off = 1; off < 16; off <<= 1)
            #pragma unroll
            for (int i = 0; i < 4; i++) rsum[i] += __shfl_xor(rsum[i], off);
        #pragma unroll
        for (int i = 0; i < 4; i++) lrow[i] = lrow[i] * alpha[i] + rsum[i];
        #pragma unroll
        for (int g = 0; g < 4; g++)
            #pragma unroll
            for (int i = 0; i < 4; i++) Oa[g][i] *= alpha[i];

        #pragma unroll
        for (int kk = 0; kk < 2; kk++) {
            const int c = kk * 4 + q4;
            const bf16x8 pf = *(const bf16x8*)(const void*)&Ps[wv][l15 * 64 + (c ^ (l15 & 7)) * 8];
            #pragma unroll
            for (int g = 0; g < 4; g++) {
                const int feat = g * 16 + l15;
                const bf16x8 vf = *(const bf16x8*)(const void*)&Vt[feat * 64 + (c ^ (feat & 7)) * 8];
                Oa[g] = __builtin_amdgcn_mfma_f32_16x16x32_bf16(pf, vf, Oa[g], 0, 0, 0);
            }
        }
    }

    float inv[4];
    #pragma unroll
    for (int i = 0; i < 4; i++) inv[i] = 1.0f / lrow[i];
    #pragma unroll
    for (int g = 0; g < 4; g++) {
        const int colo = h * 64 + g * 16 + l15;
        #pragma unroll
        for (int i = 0; i < 4; i++) {
            const int rowg = qt * 64 + wv * 16 + q4 * 4 + i;
            if (rowg < Npb)
                o[(tokbase + rowg) * DMODEL + colo] = __float2bfloat16(Oa[g][i] * inv[i]);
        }
    }
}

// ---------------------------------------------------------------------------
// MFMA GEMM: C[M,N] = epi(A[M,K] @ W[N,K]^T [+ bias]). A/resid bf16 ws,
// W/bias/scale dtype TW. 128x128 tile, BK=32, swizzled LDS. bias nullable.
// ---------------------------------------------------------------------------
template<typename TW, int ACT, bool RES, bool SCALE>
static __device__ __forceinline__ void gemm_body(
    const bf16* __restrict__ A, const TW* __restrict__ W, const TW* __restrict__ bias,
    const bf16* __restrict__ resid, const TW* __restrict__ scale_p, void* __restrict__ C,
    bool cf32, int row_off, int M, int N, int K, short* As, short* Bs)
{
    const int tid = threadIdx.x;
    const int lane = tid & 63;
    const int wv = tid >> 6;
    const int l15 = lane & 15, q4 = lane >> 4;
    const int m0 = blockIdx.y * 128, n0 = blockIdx.x * 128;
    const int wm = (wv & 1) * 64, wn = (wv >> 1) * 64;

    f32x4 acc[4][4] = {};

    for (int k0 = 0; k0 < K; k0 += 32) {
        __syncthreads();
        #pragma unroll
        for (int inst = 0; inst < 2; inst++) {
            const int s = inst * 256 + tid;
            const int row = s >> 2, pos = s & 3;
            const int c = pos ^ ((row >> 1) & 3);
            const int ra = min(m0 + row, M - 1);
            const int rb = min(n0 + row, N - 1);
            GLD_LDS16(A + (size_t)ra * K + k0 + c * 8, &As[s * 8]);
            if (sizeof(TW) == 2) {
                GLD_LDS16((const bf16*)W + (size_t)rb * K + k0 + c * 8, &Bs[s * 8]);
            } else {
                const float* wp = (const float*)W + (size_t)rb * K + k0 + c * 8;
                const float4 w0 = *(const float4*)wp;
                const float4 w1 = *(const float4*)(wp + 4);
                unsigned short hb[8];
                hb[0] = f2bf_bits(w0.x); hb[1] = f2bf_bits(w0.y);
                hb[2] = f2bf_bits(w0.z); hb[3] = f2bf_bits(w0.w);
                hb[4] = f2bf_bits(w1.x); hb[5] = f2bf_bits(w1.y);
                hb[6] = f2bf_bits(w1.z); hb[7] = f2bf_bits(w1.w);
                *(uint4*)&Bs[s * 8] = *(const uint4*)hb;
            }
        }
        __syncthreads();

        bf16x8 af[4], bfr[4];
        #pragma unroll
        for (int f = 0; f < 4; f++) {
            const int r = wm + f * 16 + l15;
            af[f] = *(const bf16x8*)(const void*)&As[r * 32 + (q4 ^ ((r >> 1) & 3)) * 8];
            const int rn = wn + f * 16 + l15;
            bfr[f] = *(const bf16x8*)(const void*)&Bs[rn * 32 + (q4 ^ ((rn >> 1) & 3)) * 8];
        }
        #pragma unroll
        for (int f = 0; f < 4; f++)
            #pragma unroll
            for (int g = 0; g < 4; g++)
                acc[f][g] = __builtin_amdgcn_mfma_f32_16x16x32_bf16(af[f], bfr[g], acc[f][g], 0, 0, 0);
    }

    const float sc = SCALE ? ld1(scale_p) : 1.0f;
    #pragma unroll
    for (int g = 0; g < 4; g++) {
        const int colg = n0 + wn + g * 16 + l15;
        if (colg >= N) continue;
        const float bv = bias ? ld1(bias + colg) : 0.f;
        #pragma unroll
        for (int f = 0; f < 4; f++) {
            const int rowb = m0 + wm + f * 16 + q4 * 4;
            #pragma unroll
            for (int i = 0; i < 4; i++) {
                const int rowg = rowb + i;
                if (rowg >= M) continue;
                float v = acc[f][g][i] + bv;
                if (ACT == 1) v = 0.5f * v * (1.0f + erff(v * 0.70710678118654752f));
                else if (ACT == 2) v = v / (1.0f + __expf(-1.702f * v));
                if (SCALE) v *= sc;
                const size_t idx = (size_t)rowg * N + colg;
                if (RES) v += bf2f(resid[idx]);
                const size_t sidx = (size_t)(rowg + row_off) * N + colg;
                if (cf32) ((float*)C)[sidx] = v;
                else ((bf16*)C)[sidx] = __float2bfloat16(v);
            }
        }
    }
}

// out_mode: 0 = bf16 out, 1 = f32 iff input dtype f32 (final output), 2 = f32
template<int ACT, bool RES, bool SCALE>
__global__ __launch_bounds__(256)
void mfma_gemm_kernel(const int* __restrict__ flag, const bf16* __restrict__ A,
                      const void* __restrict__ W, const void* __restrict__ bias,
                      const bf16* __restrict__ resid, const void* __restrict__ sp,
                      void* __restrict__ C, int out_mode, int row_off, int M, int N, int K)
{
    __shared__ __align__(16) short As[128 * 32];
    __shared__ __align__(16) short Bs[128 * 32];
    const bool cf32 = (out_mode == 2) || (out_mode == 1 && flag[0] != 0);
    if (flag[0])
        gemm_body<float, ACT, RES, SCALE>(A, (const float*)W, (const float*)bias, resid,
                                          (const float*)sp, C, cf32, row_off, M, N, K, As, Bs);
    else
        gemm_body<bf16, ACT, RES, SCALE>(A, (const bf16*)W, (const bf16*)bias, resid,
                                         (const bf16*)sp, C, cf32, row_off, M, N, K, As, Bs);
}

// ---------------------------------------------------------------------------
// Host orchestration
// ---------------------------------------------------------------------------
struct SW {
    const void *ln1_g, *ln1_b, *qkv_w, *qkv_b, *proj_w, *proj_b,
               *ln2_g, *ln2_b, *fc1_w, *fc1_b, *fc2_w, *fc2_b,
               *down_w, *down_b, *up_w, *up_b, *scale;
};

static void run_stream(const int* flag, bf16* t0, int M, int Npb, int nb, const SW& w,
                       bf16* h, bf16* big, bf16* ah, void* out, int out_row_off, hipStream_t s)
{
    const dim3 g768((DMODEL + 127) / 128, (M + 127) / 128);
    const dim3 g2304((2304 + 127) / 128, (M + 127) / 128);
    const dim3 g3072((DFF + 127) / 128, (M + 127) / 128);
    const dim3 g64((ADIM + 127) / 128, (M + 127) / 128);

    ln_kernel<<<M, 256, 0, s>>>(flag, t0, w.ln1_g, w.ln1_b, h);
    mfma_gemm_kernel<0, false, false><<<g2304, 256, 0, s>>>(
        flag, h, w.qkv_w, w.qkv_b, nullptr, nullptr, big, 0, 0, M, 2304, DMODEL);
    flash_attn_kernel<<<dim3((Npb + 63) / 64, H_HEADS, nb), 256, 0, s>>>(big, h, Npb);
    mfma_gemm_kernel<0, true, false><<<g768, 256, 0, s>>>(
        flag, h, w.proj_w, w.proj_b, t0, nullptr, t0, 0, 0, M, DMODEL, DMODEL);
    ln_kernel<<<M, 256, 0, s>>>(flag, t0, w.ln2_g, w.ln2_b, h);
    mfma_gemm_kernel<1, false, false><<<g3072, 256, 0, s>>>(
        flag, h, w.fc1_w, w.fc1_b, nullptr, nullptr, big, 0, 0, M, DFF, DMODEL);
    mfma_gemm_kernel<2, false, false><<<g64, 256, 0, s>>>(
        flag, h, w.down_w, w.down_b, nullptr, nullptr, ah, 0, 0, M, ADIM, DMODEL);
    mfma_gemm_kernel<0, true, false><<<g768, 256, 0, s>>>(
        flag, big, w.fc2_w, w.fc2_b, t0, nullptr, t0, 0, 0, M, DMODEL, DFF);
    mfma_gemm_kernel<0, true, true><<<g768, 256, 0, s>>>(
        flag, ah, w.up_w, w.up_b, t0, w.scale, out, 1, out_row_off, M, DMODEL, ADIM);
}

extern "C" void kernel_launch(void* const* d_in, const int* in_sizes, int n_in,
                              void* d_out, int out_size, void* d_ws, size_t ws_size,
                              hipStream_t stream)
{
    SW sw, rw;
    auto fill = [&](SW& s, int base) {
        s.ln1_g = d_in[base + 0];  s.ln1_b = d_in[base + 1];
        s.qkv_w = d_in[base + 2];  s.qkv_b = d_in[base + 3];
        s.proj_w = d_in[base + 4]; s.proj_b = d_in[base + 5];
        s.ln2_g = d_in[base + 6];  s.ln2_b = d_in[base + 7];
        s.fc1_w = d_in[base + 8];  s.fc1_b = d_in[base + 9];
        s.fc2_w = d_in[base + 10]; s.fc2_b = d_in[base + 11];
        s.down_w = d_in[base + 12]; s.down_b = d_in[base + 13];
        s.up_w = d_in[base + 14];  s.up_b = d_in[base + 15];
        s.scale = d_in[base + 16];
    };
    fill(sw, 5);
    fill(rw, 22);

    const int Mx = BATCH * NA;   // 8192
    const int My = BATCH * NV;   // 3136

    // persistent-phase buffers
    int* flag = (int*)d_ws;
    char* base = (char*)d_ws + 256;
    bf16* x1 = (bf16*)base;                base += (size_t)Mx * DMODEL * 2;
    bf16* y1 = (bf16*)base;                base += (size_t)My * DMODEL * 2;
    bf16* fused = (bf16*)base;             base += (size_t)BATCH * NLAT * DMODEL * 2;
    char* un = base;  // union region: fusion scratch, then stream buffers

    // fusion scratch inside union
    bf16* Cc = (bf16*)un;                                        // 17.4 MB
    bf16* Lb = (bf16*)(un + (size_t)MCAT * DMODEL * 2);          // 48 KB
    float* scores = (float*)(un + (size_t)(MCAT + 64) * DMODEL * 2);       // 1.45 MB
    float* P = (float*)((char*)scores + (size_t)MCAT * NLAT * 4 + 256);    // 1.57 MB

    // stream buffers inside union
    const size_t stream_need_big = ((size_t)Mx * DMODEL + (size_t)Mx * DFF + (size_t)Mx * ADIM) * 2;
    const size_t fixed = 256 + ((size_t)Mx * DMODEL + (size_t)My * DMODEL + (size_t)BATCH * NLAT * DMODEL) * 2;
    const bool big_ws = ws_size >= fixed + stream_need_big;
    const int hrows = big_ws ? Mx : My;
    bf16* h  = (bf16*)un;
    bf16* big = h + (size_t)hrows * DMODEL;
    bf16* ah = big + (size_t)hrows * DFF;

    detect_dtype_kernel<<<1, 64, 0, stream>>>((const unsigned short*)d_in[0], flag);

    // --- fusion: pack -> scores GEMM -> softmax -> weighted sum ---
    pack_concat_kernel<<<MCAT + NLAT, 256, 0, stream>>>(flag, d_in[0], d_in[1], d_in[2], Cc, Lb);
    mfma_gemm_kernel<0, false, false><<<dim3(1, (MCAT + 127) / 128), 256, 0, stream>>>(
        flag + 1, Cc, Lb, nullptr, nullptr, nullptr, scores, 2, 0, MCAT, NLAT, DMODEL);
    fusion_softmax_kernel<<<BATCH * NLAT, 64, 0, stream>>>(scores, P);
    fusion_wsum_kernel<<<dim3(DMODEL / 128, BATCH), 256, 0, stream>>>(Cc, P, fused);

    attend_fused_kernel<<<BATCH * NA, 256, 0, stream>>>(flag, d_in[0], fused, d_in[3], x1, NA);
    attend_fused_kernel<<<BATCH * NV, 256, 0, stream>>>(flag, d_in[1], fused, d_in[4], y1, NV);

    // --- transformer streams ---
    if (big_ws) {
        run_stream(flag, x1, Mx, NA, BATCH, sw, h, big, ah, d_out, 0, stream);
    } else {
        const int MCH = 2048;  // 4 batch items per chunk
        for (int c = 0; c < Mx / MCH; c++)
            run_stream(flag, x1 + (size_t)c * MCH * DMODEL, MCH, NA, MCH / NA, sw,
                       h, big, ah, d_out, c * MCH, stream);
    }
    run_stream(flag, y1, My, NV, BATCH, rw, h, big, ah, d_out, Mx, stream);
}